// Round 14
// baseline (507.957 us; speedup 1.0000x reference)
//
#include <hip/hip_runtime.h>
#include <math.h>

// Problem constants
#define B_DIM 8
#define T_DIM 4096
#define K_DIM 1024   // IN_DIM
#define H_DIM 1024   // HIDDEN
#define M_DIM (B_DIM * T_DIM)   // 32768 rows

typedef short bf16x8 __attribute__((ext_vector_type(8)));   // 8 bf16 = 4 VGPRs
typedef float f32x4  __attribute__((ext_vector_type(4)));

// ---------- helpers ----------
__device__ __forceinline__ unsigned short f2bf(float f) {
  unsigned int u = __builtin_bit_cast(unsigned int, f);
  u += 0x7FFFu + ((u >> 16) & 1u);   // round-to-nearest-even
  return (unsigned short)(u >> 16);
}

__device__ __forceinline__ void gload_lds16(const void* g, void* l) {
  __builtin_amdgcn_global_load_lds(
      (const __attribute__((address_space(1))) unsigned int*)g,
      (__attribute__((address_space(3))) unsigned int*)l, 16, 0, 0);
}

__device__ __forceinline__ float softplus_fast(float x) {
  float e = __expf(-fabsf(x));
  return fmaxf(x, 0.f) + __logf(1.f + e);
}

// fast tanh: 1 - 2/(e^{2x}+1). e=inf -> 1, e=0 -> -1 (correct saturation).
__device__ __forceinline__ float tanh_fast(float x) {
  float e = __expf(2.f * x);
  return 1.f - 2.f * __builtin_amdgcn_rcpf(e + 1.f);
}

// ---------- f32 -> bf16 convert (8 elems/thread) ----------
__global__ __launch_bounds__(256) void k_cvt(const float* __restrict__ in,
                                             unsigned short* __restrict__ out,
                                             int n8) {
  int i = blockIdx.x * 256 + threadIdx.x;
  if (i >= n8) return;
  float4 v0 = ((const float4*)in)[i * 2 + 0];
  float4 v1 = ((const float4*)in)[i * 2 + 1];
  bf16x8 r;
  r[0] = (short)f2bf(v0.x); r[1] = (short)f2bf(v0.y);
  r[2] = (short)f2bf(v0.z); r[3] = (short)f2bf(v0.w);
  r[4] = (short)f2bf(v1.x); r[5] = (short)f2bf(v1.y);
  r[6] = (short)f2bf(v1.z); r[7] = (short)f2bf(v1.w);
  ((bf16x8*)out)[i] = r;
}

// ---------- megakernel v5: A-direct / B-stationary / barrier-free ----------
// Grid = 512 blocks (batch = wg&7 -> XCD; 16 cols) x 256 thr (4 waves = 4
// scan chunks), 2 blocks/CU. R14 model: LDS bandwidth + barrier lockstep was
// the wall (168 KB LDS traffic per R9 tile vs 154cy MFMA). Fix:
//  * B (16 cols x K x 2 duals = 64 KB) staged in LDS ONCE in the prologue,
//    XOR-swizzled (chunk cc holds global cc^(row&7)) -> 2-way-free reads.
//  * A read DIRECTLY global->VGPR in MFMA fragment layout: lane(fr,hi) loads
//    X[row=c*64+mm*16+fr][k=ks*32+hi*8..+8] (16B). 16 rows x 4 k-chunks per
//    instr = 16 fully-consumed 64B lines. Co-resident block wg+256 reads the
//    SAME batch panel -> L1/L2 hits.
//  * NO barriers / vmcnt drains in the K loop; 1-step register prefetch;
//    waves drift freely (TLP hides latency). Only per-m-tile epilogue syncs.
// Epilogue scan math is R9-verbatim (absmax must stay 0.01223755).
__global__ __launch_bounds__(256, 2) void k_mega(
    const unsigned short* __restrict__ Xb,    // [M][K] bf16 bits
    const unsigned short* __restrict__ Wdb,   // [H][K] bf16 bits
    const unsigned short* __restrict__ Wbb,   // [H][K] bf16 bits
    const float* __restrict__ bd,
    const float* __restrict__ bb,
    const float* __restrict__ A_log,
    const float* __restrict__ h0,             // [B][H]
    float* __restrict__ out)                  // [B][T][H]
{
  __shared__ unsigned short Bs[32 * 1024];     // 64 KiB: row v = col + 16*dual
  __shared__ float totA[4][16], totB[4][16];
  __shared__ float h_state[16];

  const int tid   = threadIdx.x;
  const int wg    = blockIdx.x;
  const int batch = wg & 7;        // == XCD (round-robin dispatch)
  const int bn    = (wg >> 3) * 16;

  const int c    = tid >> 6;       // wave = chunk row-group (0..3)
  const int lane = tid & 63;
  const int fr   = lane & 15;
  const int hi   = lane >> 4;
  const int gcol = bn + fr;

  const float bdv = bd[gcol];
  const float bbv = bb[gcol];
  const float Ah  = __expf(A_log[gcol]);

  // ---- prologue: stage FULL B (64 KB) once, XOR-swizzled source ----
  // 4096 chunks of 16B; LDS[v][cc] = global chunk cc^(v&7) of W row (bn+v&15)
#pragma unroll
  for (int jj = 0; jj < 16; jj++) {
    int idx = jj * 256 + tid;        // 0..4095
    int v   = idx >> 7;              // 0..31 (col + 16*dual)
    int cc  = idx & 127;
    int cs  = cc ^ (v & 7);
    const unsigned short* Wsrc = (v & 16) ? Wbb : Wdb;
    gload_lds16(Wsrc + (((size_t)(bn + (v & 15))) << 10) + (size_t)(cs * 8),
                (char*)Bs + idx * 16);
  }
  if (tid < 16) h_state[tid] = h0[(batch << 10) + bn + tid];
  asm volatile("s_waitcnt vmcnt(0)" ::: "memory");
  __syncthreads();

  // ---- A per-lane fragment base: row = batch*T + c*64 + fr, k = hi*8 ----
  const unsigned short* pA =
      Xb + (((size_t)(batch * T_DIM + c * 64 + fr)) << 10) + (size_t)(hi * 8);
  // frag (mt, mm, ks) at pA + mt*262144 + mm*16384 + ks*32  (elements)

  // ---- B read base: row fr (dual0) / fr+16 (dual1), swizzled chunk ----
  const char* bB = (const char*)Bs + fr * 2048;
  const int   sw = fr & 7;

  const f32x4 z4 = {0.f, 0.f, 0.f, 0.f};

  // 1-step register prefetch: sets P (even ks) and Q (odd ks)
  bf16x8 aP[4], aQ[4], bP[2], bQ[2];

#define PF_A(SET, PM, KS)                                                     \
  do {                                                                        \
    SET[0] = *(const bf16x8*)((PM) + 0 * 16384 + (KS) * 32);                  \
    SET[1] = *(const bf16x8*)((PM) + 1 * 16384 + (KS) * 32);                  \
    SET[2] = *(const bf16x8*)((PM) + 2 * 16384 + (KS) * 32);                  \
    SET[3] = *(const bf16x8*)((PM) + 3 * 16384 + (KS) * 32);                  \
  } while (0)
#define PF_B(SET, KS)                                                         \
  do {                                                                        \
    int ch = (((KS) * 4 + hi) ^ sw) * 16;                                     \
    SET[0] = *(const bf16x8*)(bB + ch);                                       \
    SET[1] = *(const bf16x8*)(bB + 32768 + ch);                               \
  } while (0)
#define MFMA8(ASET, BSET)                                                     \
  do {                                                                        \
    _Pragma("unroll")                                                         \
    for (int mm = 0; mm < 4; mm++) {                                          \
      acc[mm][0] = __builtin_amdgcn_mfma_f32_16x16x32_bf16(                   \
          ASET[mm], BSET[0], acc[mm][0], 0, 0, 0);                            \
      acc[mm][1] = __builtin_amdgcn_mfma_f32_16x16x32_bf16(                   \
          ASET[mm], BSET[1], acc[mm][1], 0, 0, 0);                            \
    }                                                                         \
  } while (0)

  const unsigned short* pm = pA;   // advances 262144 elems per m-tile
  PF_A(aP, pm, 0);
  PF_B(bP, 0);

#pragma unroll 1
  for (int mt = 0; mt < 16; mt++) {
    f32x4 acc[4][2];
#pragma unroll
    for (int m = 0; m < 4; m++) { acc[m][0] = z4; acc[m][1] = z4; }

#pragma unroll
    for (int ks = 0; ks < 32; ks++) {
      if (ks & 1) {
        // prefetch even step ks+1 (or next m-tile step 0) into P
        if (ks < 31) {
          PF_A(aP, pm, ks + 1);
          PF_B(bP, ks + 1);
        } else {
          pm += 262144;                       // next m-tile
          if (mt < 15) { PF_A(aP, pm, 0); PF_B(bP, 0); }
        }
        MFMA8(aQ, bQ);
      } else {
        PF_A(aQ, pm, ks + 1);                 // odd step into Q
        PF_B(bQ, ks + 1);
        MFMA8(aP, bP);
      }
    }

    // ---- epilogue: R9-verbatim scan math ----
    // C/D layout: col = lane&15, row-in-frag = hi*4 + r  [m89-verified].
    float rA[4], rB[4], wAp[4][4], wBp[4][4];
#pragma unroll
    for (int m = 0; m < 4; m++) {
      float A_ = 1.f, B_ = 0.f;
#pragma unroll
      for (int r = 0; r < 4; r++) {
        float z1  = acc[m][0][r] + bdv;
        float z2  = acc[m][1][r] + bbv;
        float dlt = softplus_fast(z1);
        float av  = __expf(-dlt * Ah);
        float bv  = dlt * z2;
        B_ = fmaf(av, B_, bv);          // compose (A_,B_) then (av,bv)
        A_ *= av;
        wAp[m][r] = A_; wBp[m][r] = B_; // inclusive within-run prefix
      }
      rA[m] = A_; rB[m] = B_;           // run total
    }
    // exclusive prefix over the 16 runs (t-order rho = m*4 + hi), snapshotted
    float cA = 1.f, cB = 0.f, eA[4], eB[4];
#pragma unroll
    for (int rho = 0; rho < 16; rho++) {
      if ((rho & 3) == hi) { eA[rho >> 2] = cA; eB[rho >> 2] = cB; }
      float sa = __shfl(rA[rho >> 2], (rho & 3) * 16 + fr, 64);
      float sb = __shfl(rB[rho >> 2], (rho & 3) * 16 + fr, 64);
      cB = fmaf(sa, cB, sb);
      cA *= sa;
    }
    if (hi == 0) { totA[c][fr] = cA; totB[c][fr] = cB; }
    __syncthreads();
    float hs = h_state[fr];             // state before this m-tile
#pragma unroll
    for (int cc = 0; cc < 3; cc++) {    // compose chunks before mine
      float t2 = fmaf(totA[cc][fr], hs, totB[cc][fr]);
      hs = (cc < c) ? t2 : hs;
    }
    __syncthreads();                    // all reads of h_state done
    if (c == 3 && hi == 0) h_state[fr] = fmaf(cA, hs, cB);

    // apply: h_t = (excl ∘ within-run)(hs); write tanh(h_t)
    size_t obase =
        (((size_t)(batch * T_DIM + mt * 256 + c * 64 + hi * 4)) << 10)
        + (size_t)gcol;
#pragma unroll
    for (int m = 0; m < 4; m++) {
#pragma unroll
      for (int r = 0; r < 4; r++) {
        float aT = eA[m] * wAp[m][r];
        float bT = fmaf(wAp[m][r], eB[m], wBp[m][r]);
        float h  = fmaf(aT, hs, bT);
        out[obase + ((size_t)(m * 16 + r) << 10)] = tanh_fast(h);
      }
    }
  }
#undef PF_A
#undef PF_B
#undef MFMA8
}

// ---------- launch ----------
extern "C" void kernel_launch(void* const* d_in, const int* in_sizes, int n_in,
                              void* d_out, int out_size, void* d_ws, size_t ws_size,
                              hipStream_t stream) {
  const float* x     = (const float*)d_in[0];
  const float* h0    = (const float*)d_in[1];
  const float* Wd    = (const float*)d_in[2];
  const float* bd    = (const float*)d_in[3];
  const float* Wb    = (const float*)d_in[4];
  const float* bb    = (const float*)d_in[5];
  const float* A_log = (const float*)d_in[6];
  float* out = (float*)d_out;

  char* ws = (char*)d_ws;
  unsigned short* xb  = (unsigned short*)(ws + 0);           // 64 MiB
  unsigned short* wdb = (unsigned short*)(ws + 67108864);    //  2 MiB
  unsigned short* wbb = (unsigned short*)(ws + 69206016);    //  2 MiB

  // converts
  k_cvt<<<(M_DIM * K_DIM / 8) / 256, 256, 0, stream>>>(x, xb, M_DIM * K_DIM / 8);
  k_cvt<<<(H_DIM * K_DIM / 8) / 256, 256, 0, stream>>>(Wd, wdb, H_DIM * K_DIM / 8);
  k_cvt<<<(H_DIM * K_DIM / 8) / 256, 256, 0, stream>>>(Wb, wbb, H_DIM * K_DIM / 8);

  // fused dual GEMM (A-direct, B-stationary) + chunked scan + tanh
  k_mega<<<512, 256, 0, stream>>>(xb, wdb, wbb, bd, bb, A_log, h0, out);
}

// Round 15
// 392.796 us; speedup vs baseline: 1.2932x; 1.2932x over previous
//
#include <hip/hip_runtime.h>
#include <math.h>

// Problem constants
#define B_DIM 8
#define T_DIM 4096
#define K_DIM 1024   // IN_DIM
#define H_DIM 1024   // HIDDEN
#define M_DIM (B_DIM * T_DIM)   // 32768 rows

typedef short bf16x8 __attribute__((ext_vector_type(8)));   // 8 bf16 = 4 VGPRs
typedef float f32x4  __attribute__((ext_vector_type(4)));

// ---------- helpers ----------
__device__ __forceinline__ unsigned short f2bf(float f) {
  unsigned int u = __builtin_bit_cast(unsigned int, f);
  u += 0x7FFFu + ((u >> 16) & 1u);   // round-to-nearest-even
  return (unsigned short)(u >> 16);
}

__device__ __forceinline__ void gload_lds16(const void* g, void* l) {
  __builtin_amdgcn_global_load_lds(
      (const __attribute__((address_space(1))) unsigned int*)g,
      (__attribute__((address_space(3))) unsigned int*)l, 16, 0, 0);
}

__device__ __forceinline__ float softplus_fast(float x) {
  float e = __expf(-fabsf(x));
  return fmaxf(x, 0.f) + __logf(1.f + e);
}

// fast tanh: 1 - 2/(e^{2x}+1). e=inf -> 1, e=0 -> -1 (correct saturation).
__device__ __forceinline__ float tanh_fast(float x) {
  float e = __expf(2.f * x);
  return 1.f - 2.f * __builtin_amdgcn_rcpf(e + 1.f);
}

// ---------- f32 -> bf16 convert (8 elems/thread) ----------
__global__ __launch_bounds__(256) void k_cvt(const float* __restrict__ in,
                                             unsigned short* __restrict__ out,
                                             int n8) {
  int i = blockIdx.x * 256 + threadIdx.x;
  if (i >= n8) return;
  float4 v0 = ((const float4*)in)[i * 2 + 0];
  float4 v1 = ((const float4*)in)[i * 2 + 1];
  bf16x8 r;
  r[0] = (short)f2bf(v0.x); r[1] = (short)f2bf(v0.y);
  r[2] = (short)f2bf(v0.z); r[3] = (short)f2bf(v0.w);
  r[4] = (short)f2bf(v1.x); r[5] = (short)f2bf(v1.y);
  r[6] = (short)f2bf(v1.z); r[7] = (short)f2bf(v1.w);
  ((bf16x8*)out)[i] = r;
}

// ---------- megakernel v6: fully per-wave asynchronous pipeline ------------
// Grid = 512 blocks (batch = wg&7 -> XCD; 16 cols) x 256 thr (4 waves = 4
// scan chunks), 2 blocks/CU (LDS 40.6 KB). R15 model: R9's wall is the
// per-tile barrier+vmcnt(0) lockstep (all deps are per-wave!). Fix:
//  * Each wave owns: A dbuf 2x4KB (its 64 rows x BK=32, paired-row XOR
//    layout: LDS row r holds real rows r and r+32; chunk cg = slot^(r&7),
//    real = r+32*(cg>>2), kch = cg&3 -- R13-verified conflict-free family)
//    and B single 2KB (32 vrows x 32 k, paired v/v+16, same swizzle).
//  * ZERO barriers in K loop. Per step k (issue order ...B(k),A(k+1)...):
//    vmcnt(4) drains exactly through B(k) (A(k) aged 2 steps, B(k) 1);
//    ds_read A(k),B(k); lgkmcnt(0) (reads done -> B region & A parity
//    safe to overwrite); stage B(k+1), A(k+2); 8 MFMA.
//  * 32 steps/m-tile fully unrolled -> every LDS offset is an immediate.
// Epilogue per m-tile: R9-verbatim scan math (__syncthreads drains all).
__global__ __launch_bounds__(256, 2) void k_mega(
    const unsigned short* __restrict__ Xb,    // [M][K] bf16 bits
    const unsigned short* __restrict__ Wdb,   // [H][K] bf16 bits
    const unsigned short* __restrict__ Wbb,   // [H][K] bf16 bits
    const float* __restrict__ bd,
    const float* __restrict__ bb,
    const float* __restrict__ A_log,
    const float* __restrict__ h0,             // [B][H]
    float* __restrict__ out)                  // [B][T][H]
{
  __shared__ char AW[4][2][4096];              // 32 KiB: per-wave A dbuf
  __shared__ char BW[4][2048];                 //  8 KiB: per-wave B single
  __shared__ float totA[4][16], totB[4][16];
  __shared__ float h_state[16];

  const int tid   = threadIdx.x;
  const int wg    = blockIdx.x;
  const int batch = wg & 7;        // == XCD (round-robin dispatch)
  const int bn    = (wg >> 3) * 16;

  const int c    = tid >> 6;       // wave = chunk row-group (0..3)
  const int lane = tid & 63;
  const int fr   = lane & 15;
  const int hi   = lane >> 4;
  const int gcol = bn + fr;

  const float bdv = bd[gcol];
  const float bbv = bb[gcol];
  const float Ah  = __expf(A_log[gcol]);

  // ---- A staging invariants (per wave, 4 chunks/lane/step) ----
  // idx -> LDS row r=idx>>3 (0..31), slot=idx&7; cg=slot^(r&7);
  // real row = c*64 + r + 32*(cg>>2); k-chunk = cg&3.
  const unsigned short* gA[4];
  int ldsA[4];
#pragma unroll
  for (int jj = 0; jj < 4; jj++) {
    int idx = jj * 64 + lane;      // 0..255
    int r   = idx >> 3;
    int cg  = (idx & 7) ^ (r & 7);
    int Rg  = c * 64 + r + 32 * (cg >> 2);
    ldsA[jj] = idx * 16;
    gA[jj] = Xb + (((size_t)(batch * T_DIM + Rg)) << 10)
                + (size_t)((cg & 3) * 8);
  }
  // ---- B staging invariants (per wave, 2 chunks/lane/step) ----
  const unsigned short* gB[2];
  int ldsB[2];
#pragma unroll
  for (int j = 0; j < 2; j++) {
    int idx = j * 64 + lane;       // 0..127
    int r   = idx >> 3;            // 0..15
    int cg  = (idx & 7) ^ (r & 7);
    int dual = cg >> 2;            // 0 = Wd, 1 = Wb
    ldsB[j] = idx * 16;
    const unsigned short* Wsrc = dual ? Wbb : Wdb;
    gB[j] = Wsrc + (((size_t)(bn + r)) << 10) + (size_t)((cg & 3) * 8);
  }

  // ---- ds_read bases (paired-row; slot = ((half<<2)|hi)^(fr&7)) ----
  // A: frag m rows R=m*16+fr; half = m>>1, r = R&31 -> two bases.
  const char* bA0 = AW[c][0] + fr * 128 + ((hi) ^ (fr & 7)) * 16;      // m=0,1
  const char* bA1 = AW[c][0] + fr * 128 + ((4 + hi) ^ (fr & 7)) * 16;  // m=2,3
  // B: dual 0/1 at row fr.
  const char* bB0 = BW[c] + fr * 128 + ((hi) ^ (fr & 7)) * 16;
  const char* bB1 = BW[c] + fr * 128 + ((4 + hi) ^ (fr & 7)) * 16;

// stage A for flat-step offset KOFF (elements) into parity P
#define STAGE_A(KOFF, P)                                                      \
  do {                                                                        \
    _Pragma("unroll")                                                         \
    for (int jj = 0; jj < 4; jj++)                                            \
      gload_lds16(gA[jj] + (KOFF), AW[c][P] + ldsA[jj]);                      \
  } while (0)
#define STAGE_B(KS)                                                           \
  do {                                                                        \
    _Pragma("unroll")                                                         \
    for (int j = 0; j < 2; j++)                                               \
      gload_lds16(gB[j] + (KS) * 32, BW[c] + ldsB[j]);                        \
  } while (0)

// one K step; KSC = 0..31 static; parity P = KSC&1.
// A(k+2) source offset: KSC<30 -> (KSC+2)*32 ; else next m-tile (+262144).
#define STEP(KSC)                                                             \
  do {                                                                        \
    asm volatile("s_waitcnt vmcnt(4)" ::: "memory");                          \
    bf16x8 Af[4], Bf[2];                                                      \
    Af[0] = *(const bf16x8*)(bA0 + ((KSC) & 1) * 4096);                       \
    Af[1] = *(const bf16x8*)(bA0 + ((KSC) & 1) * 4096 + 2048);                \
    Af[2] = *(const bf16x8*)(bA1 + ((KSC) & 1) * 4096);                       \
    Af[3] = *(const bf16x8*)(bA1 + ((KSC) & 1) * 4096 + 2048);                \
    Bf[0] = *(const bf16x8*)(bB0);                                            \
    Bf[1] = *(const bf16x8*)(bB1);                                            \
    asm volatile("s_waitcnt lgkmcnt(0)" ::: "memory");                        \
    __builtin_amdgcn_sched_barrier(0);                                        \
    STAGE_B(((KSC) + 1) & 31);                                                \
    STAGE_A((KSC) < 30 ? ((KSC) + 2) * 32 : 262144 + ((KSC) - 30) * 32,       \
            (KSC) & 1);                                                       \
    __builtin_amdgcn_s_setprio(1);                                            \
    _Pragma("unroll")                                                         \
    for (int mm = 0; mm < 4; mm++) {                                          \
      acc[mm][0] = __builtin_amdgcn_mfma_f32_16x16x32_bf16(                   \
          Af[mm], Bf[0], acc[mm][0], 0, 0, 0);                                \
      acc[mm][1] = __builtin_amdgcn_mfma_f32_16x16x32_bf16(                   \
          Af[mm], Bf[1], acc[mm][1], 0, 0, 0);                                \
    }                                                                         \
    __builtin_amdgcn_s_setprio(0);                                            \
  } while (0)

  // prologue: h0 + pipeline fill. Issue order A(0), B(0), A(1) so the
  // steady invariant (vmcnt(4) drains through B(k)) holds from step 0.
  if (tid < 16) h_state[tid] = h0[(batch << 10) + bn + tid];
  STAGE_A(0, 0);
  STAGE_B(0);
  STAGE_A(32, 1);

  const f32x4 z4 = {0.f, 0.f, 0.f, 0.f};

#pragma unroll 1
  for (int mt = 0; mt < 16; mt++) {
    f32x4 acc[4][2];
#pragma unroll
    for (int m = 0; m < 4; m++) { acc[m][0] = z4; acc[m][1] = z4; }

    STEP(0);  STEP(1);  STEP(2);  STEP(3);  STEP(4);  STEP(5);  STEP(6);
    STEP(7);  STEP(8);  STEP(9);  STEP(10); STEP(11); STEP(12); STEP(13);
    STEP(14); STEP(15); STEP(16); STEP(17); STEP(18); STEP(19); STEP(20);
    STEP(21); STEP(22); STEP(23); STEP(24); STEP(25); STEP(26); STEP(27);
    STEP(28); STEP(29); STEP(30); STEP(31);
    // steps 30/31 pre-staged next m-tile's steps 0/1 (mt=15: reads past the
    // batch panel into adjacent ws data -- landed into LDS, never consumed).

    // advance A bases to next m-tile (256 rows = 262144 elements)
#pragma unroll
    for (int jj = 0; jj < 4; jj++) gA[jj] += 262144;

    // ---- epilogue: R9-verbatim scan math ----
    // C/D layout: col = lane&15, row-in-frag = hi*4 + r  [m89-verified].
    float rA[4], rB[4], wAp[4][4], wBp[4][4];
#pragma unroll
    for (int m = 0; m < 4; m++) {
      float A_ = 1.f, B_ = 0.f;
#pragma unroll
      for (int r = 0; r < 4; r++) {
        float z1  = acc[m][0][r] + bdv;
        float z2  = acc[m][1][r] + bbv;
        float dlt = softplus_fast(z1);
        float av  = __expf(-dlt * Ah);
        float bv  = dlt * z2;
        B_ = fmaf(av, B_, bv);          // compose (A_,B_) then (av,bv)
        A_ *= av;
        wAp[m][r] = A_; wBp[m][r] = B_; // inclusive within-run prefix
      }
      rA[m] = A_; rB[m] = B_;           // run total
    }
    // exclusive prefix over the 16 runs (t-order rho = m*4 + hi), snapshotted
    float cA = 1.f, cB = 0.f, eA[4], eB[4];
#pragma unroll
    for (int rho = 0; rho < 16; rho++) {
      if ((rho & 3) == hi) { eA[rho >> 2] = cA; eB[rho >> 2] = cB; }
      float sa = __shfl(rA[rho >> 2], (rho & 3) * 16 + fr, 64);
      float sb = __shfl(rB[rho >> 2], (rho & 3) * 16 + fr, 64);
      cB = fmaf(sa, cB, sb);
      cA *= sa;
    }
    if (hi == 0) { totA[c][fr] = cA; totB[c][fr] = cB; }
    __syncthreads();
    float hs = h_state[fr];             // state before this m-tile
#pragma unroll
    for (int cc = 0; cc < 3; cc++) {    // compose chunks before mine
      float t2 = fmaf(totA[cc][fr], hs, totB[cc][fr]);
      hs = (cc < c) ? t2 : hs;
    }
    __syncthreads();                    // all reads of h_state done
    if (c == 3 && hi == 0) h_state[fr] = fmaf(cA, hs, cB);

    // apply: h_t = (excl ∘ within-run)(hs); write tanh(h_t)
    size_t obase =
        (((size_t)(batch * T_DIM + mt * 256 + c * 64 + hi * 4)) << 10)
        + (size_t)gcol;
#pragma unroll
    for (int m = 0; m < 4; m++) {
#pragma unroll
      for (int r = 0; r < 4; r++) {
        float aT = eA[m] * wAp[m][r];
        float bT = fmaf(wAp[m][r], eB[m], wBp[m][r]);
        float h  = fmaf(aT, hs, bT);
        out[obase + ((size_t)(m * 16 + r) << 10)] = tanh_fast(h);
      }
    }
    // __syncthreads drained vmcnt; re-fill the per-wave pipeline for mt+1
    if (mt < 15) {
      STAGE_A(0, 0);
      STAGE_B(0);
      STAGE_A(32, 1);
    }
  }
#undef STEP
#undef STAGE_A
#undef STAGE_B
}

// ---------- launch ----------
extern "C" void kernel_launch(void* const* d_in, const int* in_sizes, int n_in,
                              void* d_out, int out_size, void* d_ws, size_t ws_size,
                              hipStream_t stream) {
  const float* x     = (const float*)d_in[0];
  const float* h0    = (const float*)d_in[1];
  const float* Wd    = (const float*)d_in[2];
  const float* bd    = (const float*)d_in[3];
  const float* Wb    = (const float*)d_in[4];
  const float* bb    = (const float*)d_in[5];
  const float* A_log = (const float*)d_in[6];
  float* out = (float*)d_out;

  char* ws = (char*)d_ws;
  unsigned short* xb  = (unsigned short*)(ws + 0);           // 64 MiB
  unsigned short* wdb = (unsigned short*)(ws + 67108864);    //  2 MiB
  unsigned short* wbb = (unsigned short*)(ws + 69206016);    //  2 MiB

  // converts
  k_cvt<<<(M_DIM * K_DIM / 8) / 256, 256, 0, stream>>>(x, xb, M_DIM * K_DIM / 8);
  k_cvt<<<(H_DIM * K_DIM / 8) / 256, 256, 0, stream>>>(Wd, wdb, H_DIM * K_DIM / 8);
  k_cvt<<<(H_DIM * K_DIM / 8) / 256, 256, 0, stream>>>(Wb, wbb, H_DIM * K_DIM / 8);

  // fused dual GEMM (per-wave async pipeline) + chunked scan + tanh
  k_mega<<<512, 256, 0, stream>>>(xb, wdb, wbb, bd, bb, A_log, h0, out);
}

// Round 16
// 333.385 us; speedup vs baseline: 1.5236x; 1.1782x over previous
//
#include <hip/hip_runtime.h>
#include <math.h>

// Problem constants
#define B_DIM 8
#define T_DIM 4096
#define K_DIM 1024   // IN_DIM
#define H_DIM 1024   // HIDDEN
#define M_DIM (B_DIM * T_DIM)   // 32768 rows
#define BK 64
#define NTT 256             // 16 m-tiles x 16 k-tiles per block

typedef short bf16x8 __attribute__((ext_vector_type(8)));   // 8 bf16 = 4 VGPRs
typedef float f32x4  __attribute__((ext_vector_type(4)));

// ---------- helpers ----------
__device__ __forceinline__ unsigned short f2bf(float f) {
  unsigned int u = __builtin_bit_cast(unsigned int, f);
  u += 0x7FFFu + ((u >> 16) & 1u);   // round-to-nearest-even
  return (unsigned short)(u >> 16);
}

__device__ __forceinline__ void gload_lds16(const void* g, void* l) {
  __builtin_amdgcn_global_load_lds(
      (const __attribute__((address_space(1))) unsigned int*)g,
      (__attribute__((address_space(3))) unsigned int*)l, 16, 0, 0);
}

__device__ __forceinline__ float softplus_fast(float x) {
  float e = __expf(-fabsf(x));
  return fmaxf(x, 0.f) + __logf(1.f + e);
}

// fast tanh: 1 - 2/(e^{2x}+1). e=inf -> 1, e=0 -> -1 (correct saturation).
__device__ __forceinline__ float tanh_fast(float x) {
  float e = __expf(2.f * x);
  return 1.f - 2.f * __builtin_amdgcn_rcpf(e + 1.f);
}

// ---------- f32 -> bf16 convert (8 elems/thread) ----------
__global__ __launch_bounds__(256) void k_cvt(const float* __restrict__ in,
                                             unsigned short* __restrict__ out,
                                             int n8) {
  int i = blockIdx.x * 256 + threadIdx.x;
  if (i >= n8) return;
  float4 v0 = ((const float4*)in)[i * 2 + 0];
  float4 v1 = ((const float4*)in)[i * 2 + 1];
  bf16x8 r;
  r[0] = (short)f2bf(v0.x); r[1] = (short)f2bf(v0.y);
  r[2] = (short)f2bf(v0.z); r[3] = (short)f2bf(v0.w);
  r[4] = (short)f2bf(v1.x); r[5] = (short)f2bf(v1.y);
  r[6] = (short)f2bf(v1.z); r[7] = (short)f2bf(v1.w);
  ((bf16x8*)out)[i] = r;
}

// ---------- megakernel (R9 consolidated): dual GEMM + online scan + tanh ---
// Grid = 8 batches x 64 col-tiles(16 cols) = 512 blocks x 256 thr (4 waves)
// -> 2 blocks/CU (LDS 74.75 KB). Best measured structure (R9: 304.6 us).
// Each block owns a (batch, 16-col) T-chain: 16 m-tiles of 256 rows.
// Virtual B (32 vrows): vrow[0:16)=Wd cols, [16:32)=Wb cols, so each wave's
// acc[m][0]=z1, acc[m][1]=z2 for the SAME 16 real cols. 4 waves = 4 chunks
// of 64 t-steps. Per m-tile epilogue: per-lane 4-run affine products ->
// 16-step shfl exclusive-prefix scan -> chunk totals via LDS -> h_state
// (16 f32 LDS) carried across m-tiles -> apply + tanh + single out write.
// T2 XOR swizzle via pre-swizzled global source; zero-VALU ds_read bases.
// R16 delta vs R9: s_setprio removed (m190: hurts lockstep GEMM ~1.5%).
__global__ __launch_bounds__(256, 2) void k_mega(
    const unsigned short* __restrict__ Xb,    // [M][K] bf16 bits
    const unsigned short* __restrict__ Wdb,   // [H][K] bf16 bits
    const unsigned short* __restrict__ Wbb,   // [H][K] bf16 bits
    const float* __restrict__ bd,
    const float* __restrict__ bb,
    const float* __restrict__ A_log,
    const float* __restrict__ h0,             // [B][H]
    float* __restrict__ out)                  // [B][T][H]
{
  __shared__ unsigned short As[2][256 * BK];   // 64 KiB
  __shared__ unsigned short Bs[2][32 * BK];    //  8 KiB
  __shared__ float totA[4][16], totB[4][16];   // chunk affine totals
  __shared__ float h_state[16];                // scan state per col

  const int tid   = threadIdx.x;
  const int wg    = blockIdx.x;
  const int batch = wg & 7;        // == XCD (round-robin dispatch)
  const int jn    = wg >> 3;       // 0..63 col-tile
  const int bn    = jn * 16;

  const int w    = tid >> 6;       // wave = chunk row-group c (0..3)
  const int lane = tid & 63;
  const int c    = w;
  const int fr   = lane & 15;      // column within 16
  const int hi   = lane >> 4;      // row quad
  const int gcol = bn + fr;

  // per-thread column scalars
  const float bdv = bd[gcol];
  const float bbv = bb[gcol];
  const float Ah  = __expf(A_log[gcol]);

  // ---- staging invariants: pre-swizzled global sources (cg = c^(row&7)) --
  const unsigned short* gA[8];
  int ldsA[8];
#pragma unroll
  for (int jj = 0; jj < 8; jj++) {
    int idx = jj * 256 + tid;      // 0..2047, row 0..255
    int row = idx >> 3;
    int cg  = (idx & 7) ^ (row & 7);
    ldsA[jj] = idx * 16;
    gA[jj] = Xb + (((size_t)(batch * T_DIM + row)) << 10) + (size_t)(cg * 8);
  }
  const unsigned short* gB;
  int ldsB;
  {
    int idx = tid;                 // 256 chunks, vrow 0..31
    int vr  = idx >> 3;
    int cg  = (idx & 7) ^ (vr & 7);
    ldsB = idx * 16;
    int h = bn + (vr & 15);
    const unsigned short* Wsrc = (vr & 16) ? Wbb : Wdb;
    gB = Wsrc + (((size_t)h) << 10) + (size_t)(cg * 8);
  }

  // ---- ds_read bases: swizzled chunk hi^(fr&7) is fragment-independent ---
  const int ch0 = hi ^ (fr & 7);
  const char* bA0 = (const char*)As + ((c * 64 + fr) * 128 + ch0 * 16);
  const char* bA1 = (const char*)As + ((c * 64 + fr) * 128 + (ch0 ^ 4) * 16);
  const char* bB0 = (const char*)Bs + (fr * 128 + ch0 * 16);
  const char* bB1 = (const char*)Bs + (fr * 128 + (ch0 ^ 4) * 16);

// tile tt = mt*16 + kt; A elem-offset = mt*256*1024 + kt*64
#define STAGE(TT, D)                                                          \
  do {                                                                        \
    int aOff = (((TT) >> 4) << 18) + (((TT) & 15) << 6);                      \
    int bOff = ((TT) & 15) << 6;                                              \
    _Pragma("unroll")                                                         \
    for (int jj = 0; jj < 8; jj++)                                            \
      gload_lds16(gA[jj] + aOff, (char*)As[D] + ldsA[jj]);                    \
    gload_lds16(gB + bOff, (char*)Bs[D] + ldsB);                              \
  } while (0)

#define TILE(TT, D)                                                           \
  do {                                                                        \
    if ((TT) < NTT - 1) STAGE((TT) + 1, (D) ^ 1);                             \
    bf16x8 Af[8], Bf[4];                                                      \
    _Pragma("unroll")                                                         \
    for (int mm = 0; mm < 4; mm++) {                                          \
      Af[mm * 2 + 0] = *(const bf16x8*)(bA0 + (D) * 32768 + mm * 2048);       \
      Af[mm * 2 + 1] = *(const bf16x8*)(bA1 + (D) * 32768 + mm * 2048);       \
    }                                                                         \
    _Pragma("unroll")                                                         \
    for (int nn = 0; nn < 2; nn++) {                                          \
      Bf[nn * 2 + 0] = *(const bf16x8*)(bB0 + (D) * 4096 + nn * 2048);        \
      Bf[nn * 2 + 1] = *(const bf16x8*)(bB1 + (D) * 4096 + nn * 2048);        \
    }                                                                         \
    _Pragma("unroll")                                                         \
    for (int mm = 0; mm < 4; mm++)                                            \
      _Pragma("unroll")                                                       \
      for (int nn = 0; nn < 2; nn++)                                          \
        _Pragma("unroll")                                                     \
        for (int kk = 0; kk < 2; kk++)                                        \
          acc[mm][nn] = __builtin_amdgcn_mfma_f32_16x16x32_bf16(              \
              Af[mm * 2 + kk], Bf[nn * 2 + kk], acc[mm][nn], 0, 0, 0);        \
    asm volatile("s_waitcnt vmcnt(0)" ::: "memory");                          \
    __builtin_amdgcn_s_barrier();                                             \
  } while (0)

  // prologue: stage tile 0, init scan state from h0
  STAGE(0, 0);
  if (tid < 16) h_state[tid] = h0[(batch << 10) + bn + tid];
  asm volatile("s_waitcnt vmcnt(0)" ::: "memory");
  __syncthreads();

  const f32x4 z4 = {0.f, 0.f, 0.f, 0.f};

#pragma unroll 1
  for (int mt = 0; mt < 16; mt++) {
    f32x4 acc[4][2];
#pragma unroll
    for (int m = 0; m < 4; m++) { acc[m][0] = z4; acc[m][1] = z4; }

#pragma unroll 1
    for (int kp = 0; kp < 8; kp++) {
      int tt = mt * 16 + kp * 2;
      TILE(tt, 0);
      TILE(tt + 1, 1);
    }

    // ---- epilogue: nonlinearity + within-chunk prefix scan + apply -------
    // C/D layout: col = lane&15, row-in-frag = hi*4 + r  [m89-verified].
    // t within chunk = m*16 + hi*4 + r; run = 4 consecutive t per (m,hi).
    float rA[4], rB[4], wAp[4][4], wBp[4][4];
#pragma unroll
    for (int m = 0; m < 4; m++) {
      float A_ = 1.f, B_ = 0.f;
#pragma unroll
      for (int r = 0; r < 4; r++) {
        float z1  = acc[m][0][r] + bdv;
        float z2  = acc[m][1][r] + bbv;
        float dlt = softplus_fast(z1);
        float av  = __expf(-dlt * Ah);
        float bv  = dlt * z2;
        B_ = fmaf(av, B_, bv);          // compose (A_,B_) then (av,bv)
        A_ *= av;
        wAp[m][r] = A_; wBp[m][r] = B_; // inclusive within-run prefix
      }
      rA[m] = A_; rB[m] = B_;           // run total
    }
    // exclusive prefix over the 16 runs (t-order rho = m*4 + hi), snapshotted
    float cA = 1.f, cB = 0.f, eA[4], eB[4];
#pragma unroll
    for (int rho = 0; rho < 16; rho++) {
      if ((rho & 3) == hi) { eA[rho >> 2] = cA; eB[rho >> 2] = cB; }
      float sa = __shfl(rA[rho >> 2], (rho & 3) * 16 + fr, 64);
      float sb = __shfl(rB[rho >> 2], (rho & 3) * 16 + fr, 64);
      cB = fmaf(sa, cB, sb);
      cA *= sa;
    }
    // (cA,cB) = full chunk total
    if (hi == 0) { totA[c][fr] = cA; totB[c][fr] = cB; }
    __syncthreads();
    float hs = h_state[fr];             // state before this m-tile
#pragma unroll
    for (int cc = 0; cc < 3; cc++) {    // compose chunks before mine
      float t2 = fmaf(totA[cc][fr], hs, totB[cc][fr]);
      hs = (cc < c) ? t2 : hs;
    }
    __syncthreads();                    // all reads of h_state done
    if (c == 3 && hi == 0) h_state[fr] = fmaf(cA, hs, cB);

    // apply: h_t = (excl ∘ within-run) applied to hs; write tanh(h_t)
    size_t obase = (((size_t)(batch * T_DIM + mt * 256 + c * 64 + hi * 4)) << 10)
                   + (size_t)gcol;
#pragma unroll
    for (int m = 0; m < 4; m++) {
#pragma unroll
      for (int r = 0; r < 4; r++) {
        float aT = eA[m] * wAp[m][r];
        float bT = fmaf(wAp[m][r], eB[m], wBp[m][r]);
        float h  = fmaf(aT, hs, bT);
        out[obase + ((size_t)(m * 16 + r) << 10)] = tanh_fast(h);
      }
    }
  }
#undef TILE
#undef STAGE
}

// ---------- launch ----------
extern "C" void kernel_launch(void* const* d_in, const int* in_sizes, int n_in,
                              void* d_out, int out_size, void* d_ws, size_t ws_size,
                              hipStream_t stream) {
  const float* x     = (const float*)d_in[0];
  const float* h0    = (const float*)d_in[1];
  const float* Wd    = (const float*)d_in[2];
  const float* bd    = (const float*)d_in[3];
  const float* Wb    = (const float*)d_in[4];
  const float* bb    = (const float*)d_in[5];
  const float* A_log = (const float*)d_in[6];
  float* out = (float*)d_out;

  char* ws = (char*)d_ws;
  unsigned short* xb  = (unsigned short*)(ws + 0);           // 64 MiB
  unsigned short* wdb = (unsigned short*)(ws + 67108864);    //  2 MiB
  unsigned short* wbb = (unsigned short*)(ws + 69206016);    //  2 MiB

  // converts
  k_cvt<<<(M_DIM * K_DIM / 8) / 256, 256, 0, stream>>>(x, xb, M_DIM * K_DIM / 8);
  k_cvt<<<(H_DIM * K_DIM / 8) / 256, 256, 0, stream>>>(Wd, wdb, H_DIM * K_DIM / 8);
  k_cvt<<<(H_DIM * K_DIM / 8) / 256, 256, 0, stream>>>(Wb, wbb, H_DIM * K_DIM / 8);

  // fused dual GEMM + chunked scan + tanh; 512 blocks (2/CU), 256 thr
  k_mega<<<512, 256, 0, stream>>>(xb, wdb, wbb, bd, bb, A_log, h0, out);
}

// Round 17
// 299.279 us; speedup vs baseline: 1.6973x; 1.1140x over previous
//
#include <hip/hip_runtime.h>
#include <math.h>

// Problem constants
#define B_DIM 8
#define T_DIM 4096
#define K_DIM 1024   // IN_DIM
#define H_DIM 1024   // HIDDEN
#define M_DIM (B_DIM * T_DIM)   // 32768 rows
#define BK 64
#define NTT 256             // 16 m-tiles x 16 k-tiles per block

#define NX8 (M_DIM * K_DIM / 8)          // 4194304 x-chunks
#define NW8 (H_DIM * K_DIM / 8)          //  131072 per weight
#define NCVT (NX8 + 2 * NW8)             // total 8-elem chunks

typedef short bf16x8 __attribute__((ext_vector_type(8)));   // 8 bf16 = 4 VGPRs
typedef float f32x4  __attribute__((ext_vector_type(4)));

// ---------- helpers ----------
__device__ __forceinline__ unsigned short f2bf(float f) {
  unsigned int u = __builtin_bit_cast(unsigned int, f);
  u += 0x7FFFu + ((u >> 16) & 1u);   // round-to-nearest-even
  return (unsigned short)(u >> 16);
}

__device__ __forceinline__ void gload_lds16(const void* g, void* l) {
  __builtin_amdgcn_global_load_lds(
      (const __attribute__((address_space(1))) unsigned int*)g,
      (__attribute__((address_space(3))) unsigned int*)l, 16, 0, 0);
}

__device__ __forceinline__ float softplus_fast(float x) {
  float e = __expf(-fabsf(x));
  return fmaxf(x, 0.f) + __logf(1.f + e);
}

// fast tanh: 1 - 2/(e^{2x}+1). e=inf -> 1, e=0 -> -1 (correct saturation).
__device__ __forceinline__ float tanh_fast(float x) {
  float e = __expf(2.f * x);
  return 1.f - 2.f * __builtin_amdgcn_rcpf(e + 1.f);
}

// ---------- fused f32 -> bf16 convert: x, Wd, Wb in ONE launch ----------
__global__ __launch_bounds__(256) void k_cvt3(const float* __restrict__ x,
                                              const float* __restrict__ Wd,
                                              const float* __restrict__ Wb,
                                              unsigned short* __restrict__ xb,
                                              unsigned short* __restrict__ wdb,
                                              unsigned short* __restrict__ wbb) {
  int i = blockIdx.x * 256 + threadIdx.x;
  if (i >= NCVT) return;
  const float* src;
  unsigned short* dst;
  int j;
  if (i < NX8)                 { src = x;  dst = xb;  j = i; }
  else if (i < NX8 + NW8)      { src = Wd; dst = wdb; j = i - NX8; }
  else                         { src = Wb; dst = wbb; j = i - NX8 - NW8; }
  float4 v0 = ((const float4*)src)[j * 2 + 0];
  float4 v1 = ((const float4*)src)[j * 2 + 1];
  bf16x8 r;
  r[0] = (short)f2bf(v0.x); r[1] = (short)f2bf(v0.y);
  r[2] = (short)f2bf(v0.z); r[3] = (short)f2bf(v0.w);
  r[4] = (short)f2bf(v1.x); r[5] = (short)f2bf(v1.y);
  r[6] = (short)f2bf(v1.z); r[7] = (short)f2bf(v1.w);
  ((bf16x8*)dst)[j] = r;
}

// ---------- megakernel (R9 verbatim): dual GEMM + online scan + tanh -------
// Grid = 8 batches x 64 col-tiles(16 cols) = 512 blocks x 256 thr (4 waves)
// -> 2 blocks/CU (LDS 74.75 KB). Measured best (R9: 304.6 us total).
// Each block owns a (batch, 16-col) T-chain: 16 m-tiles of 256 rows.
// Virtual B (32 vrows): vrow[0:16)=Wd cols, [16:32)=Wb cols, so each wave's
// acc[m][0]=z1, acc[m][1]=z2 for the SAME 16 real cols. 4 waves = 4 chunks
// of 64 t-steps. Per m-tile epilogue: per-lane 4-run affine products ->
// 16-step shfl exclusive-prefix scan -> chunk totals via LDS -> h_state
// (16 f32 LDS) carried across m-tiles -> apply + tanh + single out write.
// T2 XOR swizzle via pre-swizzled global source; zero-VALU ds_read bases.
// s_setprio(1) around MFMA: +5% HERE (R16 A/B: removing it cost 304.6->333)
// -- pays because the 2 co-resident blocks drift out of phase.
__global__ __launch_bounds__(256, 2) void k_mega(
    const unsigned short* __restrict__ Xb,    // [M][K] bf16 bits
    const unsigned short* __restrict__ Wdb,   // [H][K] bf16 bits
    const unsigned short* __restrict__ Wbb,   // [H][K] bf16 bits
    const float* __restrict__ bd,
    const float* __restrict__ bb,
    const float* __restrict__ A_log,
    const float* __restrict__ h0,             // [B][H]
    float* __restrict__ out)                  // [B][T][H]
{
  __shared__ unsigned short As[2][256 * BK];   // 64 KiB
  __shared__ unsigned short Bs[2][32 * BK];    //  8 KiB
  __shared__ float totA[4][16], totB[4][16];   // chunk affine totals
  __shared__ float h_state[16];                // scan state per col

  const int tid   = threadIdx.x;
  const int wg    = blockIdx.x;
  const int batch = wg & 7;        // == XCD (round-robin dispatch)
  const int jn    = wg >> 3;       // 0..63 col-tile
  const int bn    = jn * 16;

  const int w    = tid >> 6;       // wave = chunk row-group c (0..3)
  const int lane = tid & 63;
  const int c    = w;
  const int fr   = lane & 15;      // column within 16
  const int hi   = lane >> 4;      // row quad
  const int gcol = bn + fr;

  // per-thread column scalars
  const float bdv = bd[gcol];
  const float bbv = bb[gcol];
  const float Ah  = __expf(A_log[gcol]);

  // ---- staging invariants: pre-swizzled global sources (cg = c^(row&7)) --
  const unsigned short* gA[8];
  int ldsA[8];
#pragma unroll
  for (int jj = 0; jj < 8; jj++) {
    int idx = jj * 256 + tid;      // 0..2047, row 0..255
    int row = idx >> 3;
    int cg  = (idx & 7) ^ (row & 7);
    ldsA[jj] = idx * 16;
    gA[jj] = Xb + (((size_t)(batch * T_DIM + row)) << 10) + (size_t)(cg * 8);
  }
  const unsigned short* gB;
  int ldsB;
  {
    int idx = tid;                 // 256 chunks, vrow 0..31
    int vr  = idx >> 3;
    int cg  = (idx & 7) ^ (vr & 7);
    ldsB = idx * 16;
    int h = bn + (vr & 15);
    const unsigned short* Wsrc = (vr & 16) ? Wbb : Wdb;
    gB = Wsrc + (((size_t)h) << 10) + (size_t)(cg * 8);
  }

  // ---- ds_read bases: swizzled chunk hi^(fr&7) is fragment-independent ---
  const int ch0 = hi ^ (fr & 7);
  const char* bA0 = (const char*)As + ((c * 64 + fr) * 128 + ch0 * 16);
  const char* bA1 = (const char*)As + ((c * 64 + fr) * 128 + (ch0 ^ 4) * 16);
  const char* bB0 = (const char*)Bs + (fr * 128 + ch0 * 16);
  const char* bB1 = (const char*)Bs + (fr * 128 + (ch0 ^ 4) * 16);

// tile tt = mt*16 + kt; A elem-offset = mt*256*1024 + kt*64
#define STAGE(TT, D)                                                          \
  do {                                                                        \
    int aOff = (((TT) >> 4) << 18) + (((TT) & 15) << 6);                      \
    int bOff = ((TT) & 15) << 6;                                              \
    _Pragma("unroll")                                                         \
    for (int jj = 0; jj < 8; jj++)                                            \
      gload_lds16(gA[jj] + aOff, (char*)As[D] + ldsA[jj]);                    \
    gload_lds16(gB + bOff, (char*)Bs[D] + ldsB);                              \
  } while (0)

#define TILE(TT, D)                                                           \
  do {                                                                        \
    if ((TT) < NTT - 1) STAGE((TT) + 1, (D) ^ 1);                             \
    bf16x8 Af[8], Bf[4];                                                      \
    _Pragma("unroll")                                                         \
    for (int mm = 0; mm < 4; mm++) {                                          \
      Af[mm * 2 + 0] = *(const bf16x8*)(bA0 + (D) * 32768 + mm * 2048);       \
      Af[mm * 2 + 1] = *(const bf16x8*)(bA1 + (D) * 32768 + mm * 2048);       \
    }                                                                         \
    _Pragma("unroll")                                                         \
    for (int nn = 0; nn < 2; nn++) {                                          \
      Bf[nn * 2 + 0] = *(const bf16x8*)(bB0 + (D) * 4096 + nn * 2048);        \
      Bf[nn * 2 + 1] = *(const bf16x8*)(bB1 + (D) * 4096 + nn * 2048);        \
    }                                                                         \
    __builtin_amdgcn_s_setprio(1);                                            \
    _Pragma("unroll")                                                         \
    for (int mm = 0; mm < 4; mm++)                                            \
      _Pragma("unroll")                                                       \
      for (int nn = 0; nn < 2; nn++)                                          \
        _Pragma("unroll")                                                     \
        for (int kk = 0; kk < 2; kk++)                                        \
          acc[mm][nn] = __builtin_amdgcn_mfma_f32_16x16x32_bf16(              \
              Af[mm * 2 + kk], Bf[nn * 2 + kk], acc[mm][nn], 0, 0, 0);        \
    __builtin_amdgcn_s_setprio(0);                                            \
    asm volatile("s_waitcnt vmcnt(0)" ::: "memory");                          \
    __builtin_amdgcn_s_barrier();                                             \
  } while (0)

  // prologue: stage tile 0, init scan state from h0
  STAGE(0, 0);
  if (tid < 16) h_state[tid] = h0[(batch << 10) + bn + tid];
  asm volatile("s_waitcnt vmcnt(0)" ::: "memory");
  __syncthreads();

  const f32x4 z4 = {0.f, 0.f, 0.f, 0.f};

#pragma unroll 1
  for (int mt = 0; mt < 16; mt++) {
    f32x4 acc[4][2];
#pragma unroll
    for (int m = 0; m < 4; m++) { acc[m][0] = z4; acc[m][1] = z4; }

#pragma unroll 1
    for (int kp = 0; kp < 8; kp++) {
      int tt = mt * 16 + kp * 2;
      TILE(tt, 0);
      TILE(tt + 1, 1);
    }

    // ---- epilogue: nonlinearity + within-chunk prefix scan + apply -------
    // C/D layout: col = lane&15, row-in-frag = hi*4 + r  [m89-verified].
    // t within chunk = m*16 + hi*4 + r; run = 4 consecutive t per (m,hi).
    float rA[4], rB[4], wAp[4][4], wBp[4][4];
#pragma unroll
    for (int m = 0; m < 4; m++) {
      float A_ = 1.f, B_ = 0.f;
#pragma unroll
      for (int r = 0; r < 4; r++) {
        float z1  = acc[m][0][r] + bdv;
        float z2  = acc[m][1][r] + bbv;
        float dlt = softplus_fast(z1);
        float av  = __expf(-dlt * Ah);
        float bv  = dlt * z2;
        B_ = fmaf(av, B_, bv);          // compose (A_,B_) then (av,bv)
        A_ *= av;
        wAp[m][r] = A_; wBp[m][r] = B_; // inclusive within-run prefix
      }
      rA[m] = A_; rB[m] = B_;           // run total
    }
    // exclusive prefix over the 16 runs (t-order rho = m*4 + hi), snapshotted
    float cA = 1.f, cB = 0.f, eA[4], eB[4];
#pragma unroll
    for (int rho = 0; rho < 16; rho++) {
      if ((rho & 3) == hi) { eA[rho >> 2] = cA; eB[rho >> 2] = cB; }
      float sa = __shfl(rA[rho >> 2], (rho & 3) * 16 + fr, 64);
      float sb = __shfl(rB[rho >> 2], (rho & 3) * 16 + fr, 64);
      cB = fmaf(sa, cB, sb);
      cA *= sa;
    }
    // (cA,cB) = full chunk total
    if (hi == 0) { totA[c][fr] = cA; totB[c][fr] = cB; }
    __syncthreads();
    float hs = h_state[fr];             // state before this m-tile
#pragma unroll
    for (int cc = 0; cc < 3; cc++) {    // compose chunks before mine
      float t2 = fmaf(totA[cc][fr], hs, totB[cc][fr]);
      hs = (cc < c) ? t2 : hs;
    }
    __syncthreads();                    // all reads of h_state done
    if (c == 3 && hi == 0) h_state[fr] = fmaf(cA, hs, cB);

    // apply: h_t = (excl ∘ within-run) applied to hs; write tanh(h_t)
    size_t obase = (((size_t)(batch * T_DIM + mt * 256 + c * 64 + hi * 4)) << 10)
                   + (size_t)gcol;
#pragma unroll
    for (int m = 0; m < 4; m++) {
#pragma unroll
      for (int r = 0; r < 4; r++) {
        float aT = eA[m] * wAp[m][r];
        float bT = fmaf(wAp[m][r], eB[m], wBp[m][r]);
        float h  = fmaf(aT, hs, bT);
        out[obase + ((size_t)(m * 16 + r) << 10)] = tanh_fast(h);
      }
    }
  }
#undef TILE
#undef STAGE
}

// ---------- launch ----------
extern "C" void kernel_launch(void* const* d_in, const int* in_sizes, int n_in,
                              void* d_out, int out_size, void* d_ws, size_t ws_size,
                              hipStream_t stream) {
  const float* x     = (const float*)d_in[0];
  const float* h0    = (const float*)d_in[1];
  const float* Wd    = (const float*)d_in[2];
  const float* bd    = (const float*)d_in[3];
  const float* Wb    = (const float*)d_in[4];
  const float* bb    = (const float*)d_in[5];
  const float* A_log = (const float*)d_in[6];
  float* out = (float*)d_out;

  char* ws = (char*)d_ws;
  unsigned short* xb  = (unsigned short*)(ws + 0);           // 64 MiB
  unsigned short* wdb = (unsigned short*)(ws + 67108864);    //  2 MiB
  unsigned short* wbb = (unsigned short*)(ws + 69206016);    //  2 MiB

  // fused converts (one launch: x, Wd, Wb)
  k_cvt3<<<(NCVT + 255) / 256, 256, 0, stream>>>(x, Wd, Wb, xb, wdb, wbb);

  // fused dual GEMM + chunked scan + tanh; 512 blocks (2/CU), 256 thr
  k_mega<<<512, 256, 0, stream>>>(xb, wdb, wbb, bd, bb, A_log, h0, out);
}